// Round 7
// baseline (1187.733 us; speedup 1.0000x reference)
//
#include <hip/hip_runtime.h>
#include <math.h>

// ---------------------------------------------------------------------------
// GraphEncoder round 7: NO counting sort. Bucket-partition + LDS-atomic
// aggregation straight from unsorted buckets.
//   kinit  : zero masks/counters + gcur[b]=b*CAP + x->bf16 (A1 cols 0..63)
//   kflag  : dmask bits + zero masked outm rows
//   kprep  : pack W1 -> B1pk ; fold W2@Wt -> B2pk ; b2@Wt -> bc
//   kmedge : streaming masked-edge detect (dmask bitmask), medge + smask
//   kbin   : bucket scatter (dlow<<17|src) into fixed-cap regions (no hist)
//   kaggA  : per-bucket LDS f32 accumulate of x -> mean1 (A1 cols 64..127),
//            deg -> deginv
//   kgemm1 : h1 = gelu(A1 @ B1pk + b1)        (MFMA 16x16x32 bf16, no LDS)
//   kgemm2 : [hsd|z] = h1 @ B2pk (+bc)        (MFMA)
//   kaggB  : per-bucket accumulate of z for NEEDED nodes only -> finalv
//   kedgemax: edge conv + atomicMax over masked edges
//   kout   : decode
// ---------------------------------------------------------------------------

typedef __attribute__((ext_vector_type(8))) short short8;   // 8 bf16 = 4 VGPR
typedef __attribute__((ext_vector_type(4))) float f32x4;

#define NB 512          // bucket capacity table size (391 used: 256 nodes each)
#define BKN 256         // nodes per bucket
#define CAP 6144        // entries per bucket region (avg 4096, +50% headroom)
#define MEDGE_CAP 262144

__device__ __forceinline__ float gelu_f(float x) {
    const float c0 = 0.7978845608028654f; // sqrt(2/pi)
    float x3 = x * x * x;
    float t = tanhf(c0 * (x + 0.044715f * x3));
    return 0.5f * x * (1.0f + t);
}
__device__ __forceinline__ unsigned short f2b(float f) {   // f32 -> bf16 RNE
    unsigned u = __float_as_uint(f);
    u += 0x7fffu + ((u >> 16) & 1);
    return (unsigned short)(u >> 16);
}
__device__ __forceinline__ float b2f(unsigned short h) {
    return __uint_as_float(((unsigned)h) << 16);
}
__device__ __forceinline__ unsigned enc_f32(float f) {     // order-preserving
    unsigned u = __float_as_uint(f);
    return (u & 0x80000000u) ? ~u : (u | 0x80000000u);
}
__device__ __forceinline__ float dec_f32(unsigned u) {
    return (u & 0x80000000u) ? __uint_as_float(u & 0x7fffffffu)
                             : __uint_as_float(~u);
}
// fragment-order position for packed weights: element (outcol c, k)
__device__ __forceinline__ int bpkpos(int c, int k) {
    int s = k >> 5, g = (k >> 3) & 3, e = k & 7, cg = c >> 4, lm = c & 15;
    return ((s * 8 + cg) * 64 + g * 16 + lm) * 8 + e;
}

// ---------------------------------------------------------------------------
// zero small region + gcur init + x -> bf16 into A1 cols 0..63
__global__ void kinit(float4* __restrict__ z4, long n4, int* __restrict__ gcur,
                      const float* __restrict__ x, unsigned short* __restrict__ A1,
                      int N) {
    long i = (long)blockIdx.x * blockDim.x + threadIdx.x;
    if (i < n4) { z4[i] = make_float4(0.f, 0.f, 0.f, 0.f); return; }
    long j = i - n4;
    if (j < 128) {            // gcur[512] = b*CAP
        int b0 = (int)j * 4;
        *(int4*)&gcur[b0] = make_int4(b0 * CAP, (b0 + 1) * CAP,
                                      (b0 + 2) * CAP, (b0 + 3) * CAP);
        return;
    }
    j -= 128;
    if (j >= (long)N * 16) return;
    int node = (int)(j >> 4), c4 = (int)(j & 15);
    float4 v = *(const float4*)(x + (long)node * 64 + c4 * 4);
    ushort4 o;
    o.x = f2b(v.x); o.y = f2b(v.y); o.z = f2b(v.z); o.w = f2b(v.w);
    *(ushort4*)(A1 + (long)node * 128 + c4 * 4) = o;
}

// dmask bits + zero masked outm rows
__global__ void kflag(const int* __restrict__ mask, int M,
                      unsigned* __restrict__ dmask, unsigned* __restrict__ outm) {
    int i = blockIdx.x * blockDim.x + threadIdx.x;
    if (i >= M) return;
    int node = mask[i];
    atomicOr(&dmask[node >> 5], 1u << (node & 31));
    unsigned* om = outm + (long)node * 32;
#pragma unroll
    for (int c = 0; c < 32; ++c) om[c] = 0u;
}

// ---------------------------------------------------------------------------
// weight prep (129 blocks)
__global__ __launch_bounds__(256) void kprep(
    const float* __restrict__ W1r, const float* __restrict__ W1n,
    const float* __restrict__ W2r, const float* __restrict__ W2n,
    const float* __restrict__ b2,
    const float* __restrict__ Wts, const float* __restrict__ Wtd,
    unsigned short* __restrict__ B1pk, unsigned short* __restrict__ B2pk,
    float* __restrict__ bc) {
    int b = blockIdx.x, t = threadIdx.x;
    if (b < 64) {                        // B1 pack: outcol c (0..127), k (0..127)
        int idx = b * 256 + t;
        int c = idx >> 7, k = idx & 127;
        float v = (k < 64) ? W1r[k * 128 + c] : W1n[(k - 64) * 128 + c];
        B1pk[bpkpos(c, k)] = f2b(v);
    } else if (b < 128) {                // B2 fold, k wave-uniform
        int idx = (b - 64) * 256 + t;
        int c = idx & 127, k = idx >> 7;
        const float* Wrow = (c >= 64) ? (W2n + (long)k * 256) : (W2r + (long)k * 256);
        const float* Wt = ((c >> 5) & 1) ? Wtd : Wts;
        int j32 = c & 31;
        float acc = 0.f;
        for (int j = 0; j < 256; ++j) acc += Wrow[j] * Wt[j * 32 + j32];
        B2pk[bpkpos(c, k)] = f2b(acc);
    } else {
        if (t < 64) {
            const float* Wt = ((t >> 5) & 1) ? Wtd : Wts;
            int j32 = t & 31;
            float a = 0.f;
            for (int j = 0; j < 256; ++j) a += b2[j] * Wt[j * 32 + j32];
            bc[t] = a;
        }
    }
}

// ---------------------------------------------------------------------------
// streaming masked-edge detection: dmask test, emit medge + smask bits
__global__ void kmedge(const int* __restrict__ ei, int E,
                       const unsigned* __restrict__ dmask,
                       unsigned* __restrict__ smask,
                       int* __restrict__ nme, int* __restrict__ medge) {
    long e0 = ((long)blockIdx.x * blockDim.x + threadIdx.x) * 4;
    if (e0 >= E) return;
    if (e0 + 3 < E) {
        int4 dv = *(const int4*)&ei[E + e0];
        unsigned m0 = (dmask[dv.x >> 5] >> (dv.x & 31)) & 1u;
        unsigned m1 = (dmask[dv.y >> 5] >> (dv.y & 31)) & 1u;
        unsigned m2 = (dmask[dv.z >> 5] >> (dv.z & 31)) & 1u;
        unsigned m3 = (dmask[dv.w >> 5] >> (dv.w & 31)) & 1u;
        if (m0 | m1 | m2 | m3) {
            int4 sv = *(const int4*)&ei[e0];
            if (m0) { int p = atomicAdd(nme, 1); if (p < MEDGE_CAP) medge[p] = (int)e0;     atomicOr(&smask[sv.x >> 5], 1u << (sv.x & 31)); }
            if (m1) { int p = atomicAdd(nme, 1); if (p < MEDGE_CAP) medge[p] = (int)e0 + 1; atomicOr(&smask[sv.y >> 5], 1u << (sv.y & 31)); }
            if (m2) { int p = atomicAdd(nme, 1); if (p < MEDGE_CAP) medge[p] = (int)e0 + 2; atomicOr(&smask[sv.z >> 5], 1u << (sv.z & 31)); }
            if (m3) { int p = atomicAdd(nme, 1); if (p < MEDGE_CAP) medge[p] = (int)e0 + 3; atomicOr(&smask[sv.w >> 5], 1u << (sv.w & 31)); }
        }
    } else {
        for (long e = e0; e < E; ++e) {
            int d = ei[E + e];
            if ((dmask[d >> 5] >> (d & 31)) & 1u) {
                int s = ei[e];
                int p = atomicAdd(nme, 1);
                if (p < MEDGE_CAP) medge[p] = (int)e;
                atomicOr(&smask[s >> 5], 1u << (s & 31));
            }
        }
    }
}

// ---------------------------------------------------------------------------
// bucket scatter: 8 edges/thread (two int4 quads), fixed-cap regions, no hist
__global__ __launch_bounds__(256) void kbin(const int* __restrict__ ei, int E,
        int* __restrict__ gcur, unsigned* __restrict__ bkt) {
    __shared__ int hist[NB];
    __shared__ int base_[NB];
    int t = threadIdx.x;
    long e0 = (long)blockIdx.x * 2048 + t * 4;
    long e1 = e0 + 1024;
    hist[t] = 0; hist[t + 256] = 0;
    __syncthreads();
    int4 dva, sva, dvb, svb;
    int lpa0=0,lpa1=0,lpa2=0,lpa3=0, lpb0=0,lpb1=0,lpb2=0,lpb3=0;
    bool oka = (e0 + 3 < E), okb = (e1 + 3 < E);
    if (oka) {
        dva = *(const int4*)&ei[E + e0];
        sva = *(const int4*)&ei[e0];
        lpa0 = atomicAdd(&hist[dva.x >> 8], 1);
        lpa1 = atomicAdd(&hist[dva.y >> 8], 1);
        lpa2 = atomicAdd(&hist[dva.z >> 8], 1);
        lpa3 = atomicAdd(&hist[dva.w >> 8], 1);
    }
    if (okb) {
        dvb = *(const int4*)&ei[E + e1];
        svb = *(const int4*)&ei[e1];
        lpb0 = atomicAdd(&hist[dvb.x >> 8], 1);
        lpb1 = atomicAdd(&hist[dvb.y >> 8], 1);
        lpb2 = atomicAdd(&hist[dvb.z >> 8], 1);
        lpb3 = atomicAdd(&hist[dvb.w >> 8], 1);
    }
    __syncthreads();
    { int hc = hist[t];       base_[t]       = hc ? atomicAdd(&gcur[t], hc) : 0; }
    { int hc = hist[t + 256]; base_[t + 256] = hc ? atomicAdd(&gcur[t + 256], hc) : 0; }
    __syncthreads();
    if (oka) {
        bkt[base_[dva.x >> 8] + lpa0] = ((unsigned)(dva.x & 255) << 17) | (unsigned)sva.x;
        bkt[base_[dva.y >> 8] + lpa1] = ((unsigned)(dva.y & 255) << 17) | (unsigned)sva.y;
        bkt[base_[dva.z >> 8] + lpa2] = ((unsigned)(dva.z & 255) << 17) | (unsigned)sva.z;
        bkt[base_[dva.w >> 8] + lpa3] = ((unsigned)(dva.w & 255) << 17) | (unsigned)sva.w;
    }
    if (okb) {
        bkt[base_[dvb.x >> 8] + lpb0] = ((unsigned)(dvb.x & 255) << 17) | (unsigned)svb.x;
        bkt[base_[dvb.y >> 8] + lpb1] = ((unsigned)(dvb.y & 255) << 17) | (unsigned)svb.y;
        bkt[base_[dvb.z >> 8] + lpb2] = ((unsigned)(dvb.z & 255) << 17) | (unsigned)svb.z;
        bkt[base_[dvb.w >> 8] + lpb3] = ((unsigned)(dvb.w & 255) << 17) | (unsigned)svb.w;
    }
    // scalar tail (covers any partial quad)
    if (!oka) {
        for (long e = e0; e < E && e < e0 + 4; ++e) {
            int s = ei[e], d = ei[E + e];
            int p = atomicAdd(&gcur[d >> 8], 1);
            bkt[p] = ((unsigned)(d & 255) << 17) | (unsigned)s;
        }
    }
    if (!okb) {
        for (long e = e1; e < E && e < e1 + 4; ++e) {
            int s = ei[e], d = ei[E + e];
            int p = atomicAdd(&gcur[d >> 8], 1);
            bkt[p] = ((unsigned)(d & 255) << 17) | (unsigned)s;
        }
    }
}

// ---------------------------------------------------------------------------
// bucket aggregate x -> mean1 (A1 cols 64..127) + deginv.  LDS f32 acc,
// swizzle (k+n)&63, 16 lanes/edge, 4-edge unroll for MLP.
__global__ __launch_bounds__(256) void kaggA(const unsigned* __restrict__ bkt,
        const int* __restrict__ gcur, unsigned short* __restrict__ A1,
        float* __restrict__ deginv, int N) {
    __shared__ float acc[BKN * 64];
    __shared__ int degl[BKN];
    __shared__ unsigned se[2048];
    int b = blockIdx.x, t = threadIdx.x;
    int nodebase = b << 8;
    for (int i = t; i < BKN * 64; i += 256) acc[i] = 0.f;
    degl[t] = 0;
    int base = b * CAP;
    int cnt = gcur[b] - base; if (cnt > CAP) cnt = CAP;
    int g = t >> 4, L = t & 15;
    for (int c0 = 0; c0 < cnt; c0 += 2048) {
        int nst = min(2048, cnt - c0);
        __syncthreads();
        for (int i = t; i < nst; i += 256) se[i] = bkt[base + c0 + i];
        __syncthreads();
        for (int i0 = g * 4; i0 < nst; i0 += 64) {
            int nq = min(4, nst - i0);
            unsigned en[4]; ushort4 v[4]; int dl[4];
#pragma unroll
            for (int q = 0; q < 4; ++q) {
                if (q < nq) {
                    en[q] = se[i0 + q];
                    int src = en[q] & 0x1FFFF; dl[q] = en[q] >> 17;
                    v[q] = *(const ushort4*)(A1 + (long)src * 128 + L * 4);
                }
            }
#pragma unroll
            for (int q = 0; q < 4; ++q) {
                if (q < nq) {
                    int bse = dl[q] * 64, k0 = L * 4, dd = dl[q];
                    atomicAdd(&acc[bse + ((k0 + 0 + dd) & 63)], b2f(v[q].x));
                    atomicAdd(&acc[bse + ((k0 + 1 + dd) & 63)], b2f(v[q].y));
                    atomicAdd(&acc[bse + ((k0 + 2 + dd) & 63)], b2f(v[q].z));
                    atomicAdd(&acc[bse + ((k0 + 3 + dd) & 63)], b2f(v[q].w));
                    if (L == 0) atomicAdd(&degl[dd], 1);
                }
            }
        }
    }
    __syncthreads();
    int c = t & 7, nl = t >> 3;    // 8 threads/node, 32 nodes/pass
    for (int p = 0; p < BKN; p += 32) {
        int n = p + nl, node = nodebase + n;
        if (node < N) {
            float inv = 1.f / fmaxf((float)degl[n], 1.f);
            unsigned short o[8];
#pragma unroll
            for (int q = 0; q < 8; ++q) {
                int k = c * 8 + q;
                o[q] = f2b(acc[n * 64 + ((k + n) & 63)] * inv);
            }
            *(short8*)(A1 + (long)node * 128 + 64 + c * 8) = *(const short8*)o;
            if (c == 0) deginv[node] = inv;
        }
    }
}

// ---------------------------------------------------------------------------
// GEMM1: h1 = gelu(A1 @ W1 + b1), K=128, cols=128. 32 rows/wave, no LDS.
__global__ __launch_bounds__(256) void kgemm1(const unsigned short* __restrict__ A1,
                                              const unsigned short* __restrict__ B1pk,
                                              const float* __restrict__ b1,
                                              unsigned short* __restrict__ h1, int N) {
    int l = threadIdx.x & 63, wv = threadIdx.x >> 6;
    int lm = l & 15, lh = l >> 4;
    long base = (long)blockIdx.x * 128 + wv * 32;
    int r0 = (int)base + lm;      if (r0 > N - 1) r0 = N - 1;
    int r1 = (int)base + 16 + lm; if (r1 > N - 1) r1 = N - 1;
    const unsigned short* a0p = A1 + (long)r0 * 128 + lh * 8;
    const unsigned short* a1p = A1 + (long)r1 * 128 + lh * 8;
    const short8* bp = (const short8*)B1pk;
    f32x4 acc[2][8];
#pragma unroll
    for (int rg = 0; rg < 2; ++rg)
#pragma unroll
        for (int cg = 0; cg < 8; ++cg) acc[rg][cg] = (f32x4){0.f, 0.f, 0.f, 0.f};
#pragma unroll
    for (int s = 0; s < 4; ++s) {
        short8 a0 = *(const short8*)(a0p + s * 32);
        short8 a1 = *(const short8*)(a1p + s * 32);
#pragma unroll
        for (int cg = 0; cg < 8; ++cg) {
            short8 b = bp[(s * 8 + cg) * 64 + l];
            acc[0][cg] = __builtin_amdgcn_mfma_f32_16x16x32_bf16(a0, b, acc[0][cg], 0, 0, 0);
            acc[1][cg] = __builtin_amdgcn_mfma_f32_16x16x32_bf16(a1, b, acc[1][cg], 0, 0, 0);
        }
    }
#pragma unroll
    for (int cg = 0; cg < 8; ++cg) {
        float bv = b1[cg * 16 + lm];
#pragma unroll
        for (int rg = 0; rg < 2; ++rg) {
#pragma unroll
            for (int r = 0; r < 4; ++r) {
                long row = base + rg * 16 + lh * 4 + r;
                if (row < N)
                    h1[row * 128 + cg * 16 + lm] = f2b(gelu_f(acc[rg][cg][r] + bv));
            }
        }
    }
}

// GEMM2: cols 0..63 -> hsd (f32, +bc) ; cols 64..127 -> z (bf16)
__global__ __launch_bounds__(256) void kgemm2(const unsigned short* __restrict__ h1,
                                              const unsigned short* __restrict__ B2pk,
                                              const float* __restrict__ bc,
                                              float* __restrict__ hsd,
                                              unsigned short* __restrict__ z, int N) {
    int l = threadIdx.x & 63, wv = threadIdx.x >> 6;
    int lm = l & 15, lh = l >> 4;
    long base = (long)blockIdx.x * 128 + wv * 32;
    int r0 = (int)base + lm;      if (r0 > N - 1) r0 = N - 1;
    int r1 = (int)base + 16 + lm; if (r1 > N - 1) r1 = N - 1;
    const unsigned short* a0p = h1 + (long)r0 * 128 + lh * 8;
    const unsigned short* a1p = h1 + (long)r1 * 128 + lh * 8;
    const short8* bp = (const short8*)B2pk;
    f32x4 acc[2][8];
#pragma unroll
    for (int rg = 0; rg < 2; ++rg)
#pragma unroll
        for (int cg = 0; cg < 8; ++cg) acc[rg][cg] = (f32x4){0.f, 0.f, 0.f, 0.f};
#pragma unroll
    for (int s = 0; s < 4; ++s) {
        short8 a0 = *(const short8*)(a0p + s * 32);
        short8 a1 = *(const short8*)(a1p + s * 32);
#pragma unroll
        for (int cg = 0; cg < 8; ++cg) {
            short8 b = bp[(s * 8 + cg) * 64 + l];
            acc[0][cg] = __builtin_amdgcn_mfma_f32_16x16x32_bf16(a0, b, acc[0][cg], 0, 0, 0);
            acc[1][cg] = __builtin_amdgcn_mfma_f32_16x16x32_bf16(a1, b, acc[1][cg], 0, 0, 0);
        }
    }
#pragma unroll
    for (int cg = 0; cg < 4; ++cg) {          // direct part
        float bv = bc[cg * 16 + lm];
#pragma unroll
        for (int rg = 0; rg < 2; ++rg)
#pragma unroll
            for (int r = 0; r < 4; ++r) {
                long row = base + rg * 16 + lh * 4 + r;
                if (row < N) hsd[row * 64 + cg * 16 + lm] = acc[rg][cg][r] + bv;
            }
    }
#pragma unroll
    for (int cg = 4; cg < 8; ++cg) {          // neighbor part -> z (bf16)
#pragma unroll
        for (int rg = 0; rg < 2; ++rg)
#pragma unroll
            for (int r = 0; r < 4; ++r) {
                long row = base + rg * 16 + lh * 4 + r;
                if (row < N) z[row * 64 + (cg - 4) * 16 + lm] = f2b(acc[rg][cg][r]);
            }
    }
}

// ---------------------------------------------------------------------------
// bucket aggregate z for NEEDED nodes -> finalv = hsd + mean(z)
__global__ __launch_bounds__(256) void kaggB(const unsigned* __restrict__ bkt,
        const int* __restrict__ gcur, const unsigned short* __restrict__ z,
        const float* __restrict__ hsd, const float* __restrict__ deginv,
        const unsigned* __restrict__ dmask, const unsigned* __restrict__ smask,
        float* __restrict__ finalv, int N) {
    __shared__ float acc[BKN * 64];
    __shared__ unsigned se[2048];
    __shared__ unsigned char need[BKN];
    __shared__ int anyneed;
    int b = blockIdx.x, t = threadIdx.x;
    int nodebase = b << 8;
    if (t == 0) anyneed = 0;
    __syncthreads();
    {
        int node = nodebase + t;
        unsigned nd = 0;
        if (node < N) nd = ((dmask[node >> 5] | smask[node >> 5]) >> (node & 31)) & 1u;
        need[t] = (unsigned char)nd;
        if (nd) anyneed = 1;
    }
    for (int i = t; i < BKN * 64; i += 256) acc[i] = 0.f;
    __syncthreads();
    if (!anyneed) return;
    int base = b * CAP;
    int cnt = gcur[b] - base; if (cnt > CAP) cnt = CAP;
    int g = t >> 4, L = t & 15;
    for (int c0 = 0; c0 < cnt; c0 += 2048) {
        int nst = min(2048, cnt - c0);
        __syncthreads();
        for (int i = t; i < nst; i += 256) se[i] = bkt[base + c0 + i];
        __syncthreads();
        for (int i0 = g * 4; i0 < nst; i0 += 64) {
            int nq = min(4, nst - i0);
#pragma unroll
            for (int q = 0; q < 4; ++q) {
                if (q < nq) {
                    unsigned en = se[i0 + q];
                    int dl = en >> 17;
                    if (need[dl]) {
                        int src = en & 0x1FFFF;
                        ushort4 v = *(const ushort4*)(z + (long)src * 64 + L * 4);
                        int bse = dl * 64, k0 = L * 4;
                        atomicAdd(&acc[bse + ((k0 + 0 + dl) & 63)], b2f(v.x));
                        atomicAdd(&acc[bse + ((k0 + 1 + dl) & 63)], b2f(v.y));
                        atomicAdd(&acc[bse + ((k0 + 2 + dl) & 63)], b2f(v.z));
                        atomicAdd(&acc[bse + ((k0 + 3 + dl) & 63)], b2f(v.w));
                    }
                }
            }
        }
    }
    __syncthreads();
    int c = t & 7, nl = t >> 3;
    for (int p = 0; p < BKN; p += 32) {
        int n = p + nl, node = nodebase + n;
        if (node < N && need[n]) {
            float inv = deginv[node];
            const float4* hp = (const float4*)(hsd + (long)node * 64 + c * 8);
            float4 h0 = hp[0], h1v = hp[1];
            float m[8];
#pragma unroll
            for (int q = 0; q < 8; ++q) {
                int k = c * 8 + q;
                m[q] = acc[n * 64 + ((k + n) & 63)] * inv;
            }
            float4 o0, o1;
            o0.x = h0.x + m[0]; o0.y = h0.y + m[1];
            o0.z = h0.z + m[2]; o0.w = h0.w + m[3];
            o1.x = h1v.x + m[4]; o1.y = h1v.y + m[5];
            o1.z = h1v.z + m[6]; o1.w = h1v.w + m[7];
            float4* op = (float4*)(finalv + (long)node * 64 + c * 8);
            op[0] = o0; op[1] = o1;
        }
    }
}

// ---------------------------------------------------------------------------
__global__ void kedgemax(const int* __restrict__ nme, const int* __restrict__ medge,
                         const int* __restrict__ ei, const float* __restrict__ et,
                         const float* __restrict__ finalv,
                         const float* __restrict__ wt, const float* __restrict__ bt,
                         unsigned* __restrict__ outm, int E) {
    int nm = *nme; if (nm > MEDGE_CAP) nm = MEDGE_CAP;
    for (int i = blockIdx.x * blockDim.x + threadIdx.x; i < nm;
         i += gridDim.x * blockDim.x) {
        int e = medge[i];
        int s = ei[e], d = ei[E + e];
        float tm = et[e];
        const float4* a4 = (const float4*)(finalv + (long)s * 64);       // hs
        const float4* b4 = (const float4*)(finalv + (long)d * 64 + 32);  // hd
        const float4* wt4 = (const float4*)wt;
        const float4* bt4 = (const float4*)bt;
        unsigned* om = outm + (long)d * 32;
#pragma unroll
        for (int c4 = 0; c4 < 8; ++c4) {
            float4 a = a4[c4], b = b4[c4], w = wt4[c4], bb = bt4[c4];
            float v0 = gelu_f(a.x + b.x + tm * w.x + bb.x);
            float v1 = gelu_f(a.y + b.y + tm * w.y + bb.y);
            float v2 = gelu_f(a.z + b.z + tm * w.z + bb.z);
            float v3 = gelu_f(a.w + b.w + tm * w.w + bb.w);
            atomicMax(om + c4 * 4 + 0, enc_f32(v0));
            atomicMax(om + c4 * 4 + 1, enc_f32(v1));
            atomicMax(om + c4 * 4 + 2, enc_f32(v2));
            atomicMax(om + c4 * 4 + 3, enc_f32(v3));
        }
    }
}

__global__ void kout(const int* __restrict__ mask, const unsigned* __restrict__ outm,
                     float* __restrict__ out, int M) {
    int idx = blockIdx.x * blockDim.x + threadIdx.x;
    if (idx >= M * 32) return;
    int i = idx >> 5, c = idx & 31;
    float f = dec_f32(outm[(long)mask[i] * 32 + c]);
    out[idx] = isfinite(f) ? f : 0.0f;
}

// ---------------------------------------------------------------------------
extern "C" void kernel_launch(void* const* d_in, const int* in_sizes, int n_in,
                              void* d_out, int out_size, void* d_ws, size_t ws_size,
                              hipStream_t stream) {
    const float* x   = (const float*)d_in[0];
    const int*   ei  = (const int*)d_in[1];
    const float* et  = (const float*)d_in[2];
    const int*   mask= (const int*)d_in[3];
    const float* W1r = (const float*)d_in[4];
    const float* W1n = (const float*)d_in[5];
    const float* b1  = (const float*)d_in[6];
    const float* W2r = (const float*)d_in[7];
    const float* W2n = (const float*)d_in[8];
    const float* b2  = (const float*)d_in[9];
    const float* Wts = (const float*)d_in[10];
    const float* Wtd = (const float*)d_in[11];
    const float* wt  = (const float*)d_in[12];
    const float* bt  = (const float*)d_in[13];

    int N = in_sizes[0] / 64;
    int E = in_sizes[1] / 2;
    int M = in_sizes[3];

    float* ws = (float*)d_ws;
    size_t off = 0;
    size_t mw = (((size_t)N + 31) / 32 + 15) & ~(size_t)15;   // mask words, pad16
    // --- zeroed region (contiguous from ws[0]) ---
    unsigned* dmask = (unsigned*)(ws + off); off += mw;
    unsigned* smask = (unsigned*)(ws + off); off += mw;
    int*      nme   = (int*)(ws + off);      off += 16;
    size_t zero_words = off;                 // multiple of 16 -> /4 float4s
    // --- rest (not zeroed) ---
    int*      gcur  = (int*)(ws + off);      off += NB;
    unsigned* bkt   = (unsigned*)(ws + off); off += (size_t)NB * CAP;
    int*      medge = (int*)(ws + off);      off += MEDGE_CAP;
    float*    deginv= ws + off;              off += (size_t)N;
    float*    bc    = ws + off;              off += 64;
    unsigned short* B1pk = (unsigned short*)(ws + off); off += 8192;
    unsigned short* B2pk = (unsigned short*)(ws + off); off += 8192;
    unsigned short* A1   = (unsigned short*)(ws + off); off += (size_t)N * 64;
    unsigned short* h1   = (unsigned short*)(ws + off); off += (size_t)N * 64;
    float*    hsd   = ws + off;              off += (size_t)N * 64;
    unsigned short* zb   = (unsigned short*)(ws + off); off += (size_t)N * 32;
    float*    finalv= ws + off;              off += (size_t)N * 64;
    unsigned* outm  = (unsigned*)(ws + off); off += (size_t)N * 32;

    long n4z = (long)(zero_words / 4);
    long init_total = n4z + 128 + (long)N * 16;
    int nb_used = (N + 255) >> 8;                     // 391
    int binb = (int)(((long)E + 2047) / 2048);        // 782
    int medb = (int)(((long)E + 1023) / 1024);        // 1563 (4 edges/thread)

    kinit<<<(int)((init_total + 255) / 256), 256, 0, stream>>>(
        (float4*)ws, n4z, gcur, x, A1, N);
    kflag<<<(M + 255) / 256, 256, 0, stream>>>(mask, M, dmask, outm);
    kprep<<<129, 256, 0, stream>>>(W1r, W1n, W2r, W2n, b2, Wts, Wtd, B1pk, B2pk, bc);
    kmedge<<<medb, 256, 0, stream>>>(ei, E, dmask, smask, nme, medge);
    kbin<<<binb, 256, 0, stream>>>(ei, E, gcur, bkt);

    kaggA<<<nb_used, 256, 0, stream>>>(bkt, gcur, A1, deginv, N);
    kgemm1<<<(N + 127) / 128, 256, 0, stream>>>(A1, B1pk, b1, h1, N);
    kgemm2<<<(N + 127) / 128, 256, 0, stream>>>(h1, B2pk, bc, hsd, zb, N);
    kaggB<<<nb_used, 256, 0, stream>>>(bkt, gcur, zb, hsd, deginv, dmask, smask,
                                       finalv, N);

    kedgemax<<<128, 256, 0, stream>>>(nme, medge, ei, et, finalv, wt, bt, outm, E);
    kout<<<(M * 32 + 255) / 256, 256, 0, stream>>>(mask, outm, (float*)d_out, M);
}

// Round 10
// 460.959 us; speedup vs baseline: 2.5767x; 2.5767x over previous
//
#include <hip/hip_runtime.h>
#include <math.h>

// ---------------------------------------------------------------------------
// GraphEncoder round 10: R9 with the zb workspace-size bug fixed (N*16 ->
// N*32 words; zb holds N x 64 bf16 = N*32 floats; R9's undersize made finalv
// alias the top half of zb).  No other changes, to cleanly attribute time.
// Pipeline: kinit, kmix1, kmix2, kbin, kcsr, kagg1, kgemm1, kgemm2,
//           kagg3, kedgemax, kout   (11 launches)
// ---------------------------------------------------------------------------

typedef __attribute__((ext_vector_type(8))) short short8;   // 8 bf16 = 4 VGPR
typedef __attribute__((ext_vector_type(4))) float f32x4;

#define NB 512          // buckets (dst>>8), 391 used for N=100000
#define HEB 2048        // edges per hist block
#define MEDGE_CAP 262144

__device__ __forceinline__ float gelu_f(float x) {
    const float c0 = 0.7978845608028654f; // sqrt(2/pi)
    float x3 = x * x * x;
    float t = tanhf(c0 * (x + 0.044715f * x3));
    return 0.5f * x * (1.0f + t);
}
__device__ __forceinline__ unsigned short f2b(float f) {   // f32 -> bf16 RNE
    unsigned u = __float_as_uint(f);
    u += 0x7fffu + ((u >> 16) & 1);
    return (unsigned short)(u >> 16);
}
__device__ __forceinline__ float b2f(unsigned short h) {
    return __uint_as_float(((unsigned)h) << 16);
}
__device__ __forceinline__ unsigned enc_f32(float f) {     // order-preserving
    unsigned u = __float_as_uint(f);
    return (u & 0x80000000u) ? ~u : (u | 0x80000000u);
}
__device__ __forceinline__ float dec_f32(unsigned u) {
    return (u & 0x80000000u) ? __uint_as_float(u & 0x7fffffffu)
                             : __uint_as_float(~u);
}
// fragment-order position for packed weights: element (outcol c, k)
__device__ __forceinline__ int bpkpos(int c, int k) {
    int s = k >> 5, g = (k >> 3) & 3, e = k & 7, cg = c >> 4, lm = c & 15;
    return ((s * 8 + cg) * 64 + g * 16 + lm) * 8 + e;
}

// ---------------------------------------------------------------------------
// zero small region + convert x -> bf16 into A1 cols 0..63
__global__ void kinit(float4* __restrict__ z4, long n4, const float* __restrict__ x,
                      unsigned short* __restrict__ A1, int N) {
    long i = (long)blockIdx.x * blockDim.x + threadIdx.x;
    if (i < n4) { z4[i] = make_float4(0.f, 0.f, 0.f, 0.f); return; }
    long j = i - n4;
    if (j >= (long)N * 16) return;
    int node = (int)(j >> 4), c4 = (int)(j & 15);
    float4 v = *(const float4*)(x + (long)node * 64 + c4 * 4);
    ushort4 o;
    o.x = f2b(v.x); o.y = f2b(v.y); o.z = f2b(v.z); o.w = f2b(v.w);
    *(ushort4*)(A1 + (long)node * 128 + c4 * 4) = o;
}

// ---------------------------------------------------------------------------
// fused: weight prep | dmask flag + masked outm zero | pure bucket histogram
__global__ __launch_bounds__(256) void kmix1(
    const float* __restrict__ W1r, const float* __restrict__ W1n,
    const float* __restrict__ W2r, const float* __restrict__ W2n,
    const float* __restrict__ b2,
    const float* __restrict__ Wts, const float* __restrict__ Wtd,
    const int* __restrict__ ei, int E, const int* __restrict__ mask, int M, int fb,
    unsigned short* __restrict__ B1pk, unsigned short* __restrict__ B2pk,
    float* __restrict__ bc, unsigned* __restrict__ dmask,
    unsigned* __restrict__ outm, int* __restrict__ bcnt) {
    __shared__ int h[NB];
    int b = blockIdx.x, t = threadIdx.x;
    if (b < 64) {                        // B1 pack: outcol c (0..127), k (0..127)
        int idx = b * 256 + t;
        int c = idx >> 7, k = idx & 127;
        float v = (k < 64) ? W1r[k * 128 + c] : W1n[(k - 64) * 128 + c];
        B1pk[bpkpos(c, k)] = f2b(v);
    } else if (b < 128) {                // B2 fold, k wave-uniform
        int idx = (b - 64) * 256 + t;
        int c = idx & 127, k = idx >> 7;
        const float* Wrow = (c >= 64) ? (W2n + (long)k * 256) : (W2r + (long)k * 256);
        const float* Wt = ((c >> 5) & 1) ? Wtd : Wts;
        int j32 = c & 31;
        float acc = 0.f;
        for (int j = 0; j < 256; ++j) acc += Wrow[j] * Wt[j * 32 + j32];
        B2pk[bpkpos(c, k)] = f2b(acc);
    } else if (b == 128) {               // bc fold
        if (t < 64) {
            const float* Wt = ((t >> 5) & 1) ? Wtd : Wts;
            int j32 = t & 31;
            float a = 0.f;
            for (int j = 0; j < 256; ++j) a += b2[j] * Wt[j * 32 + j32];
            bc[t] = a;
        }
    } else if (b < 129 + fb) {           // dmask bits + zero masked outm rows
        int i = (b - 129) * 256 + t;
        if (i < M) {
            int node = mask[i];
            atomicOr(&dmask[node >> 5], 1u << (node & 31));
            unsigned* om = outm + (long)node * 32;
#pragma unroll
            for (int c = 0; c < 32; ++c) om[c] = 0u;
        }
    } else {                             // pure histogram, HEB edges/block
        h[t] = 0; h[t + 256] = 0;
        __syncthreads();
        long base = (long)(b - 129 - fb) * HEB;
#pragma unroll
        for (int q = 0; q < HEB / 1024; ++q) {
            long e0 = base + q * 1024 + t * 4;
            if (e0 + 3 < E) {
                int4 dv = *(const int4*)&ei[E + e0];
                atomicAdd(&h[dv.x >> 8], 1);
                atomicAdd(&h[dv.y >> 8], 1);
                atomicAdd(&h[dv.z >> 8], 1);
                atomicAdd(&h[dv.w >> 8], 1);
            } else {
                for (long e = e0; e < E && e < e0 + 4; ++e)
                    atomicAdd(&h[ei[E + e] >> 8], 1);
            }
        }
        __syncthreads();
        if (h[t]) atomicAdd(&bcnt[t], h[t]);
        if (h[t + 256]) atomicAdd(&bcnt[t + 256], h[t + 256]);
    }
}

// ---------------------------------------------------------------------------
// fused: streaming masked-edge detect (4 edges/thread) | serial bucket scan
__global__ void kmix2(const int* __restrict__ ei, int E,
                      const unsigned* __restrict__ dmask,
                      unsigned* __restrict__ smask,
                      int* __restrict__ nme, int* __restrict__ medge,
                      const int* __restrict__ bcnt, int* __restrict__ bstart,
                      int* __restrict__ gcur, int* __restrict__ rowptr,
                      int N, int medb) {
    int b = blockIdx.x;
    if (b == medb) {                     // serial bucket exclusive prefix
        if (threadIdx.x == 0) {
            int run = 0;
            for (int i = 0; i < NB; ++i) {
                bstart[i] = run; gcur[i] = run; run += bcnt[i];
            }
            rowptr[N] = run;             // == E
        }
        return;
    }
    long e0 = ((long)b * 256 + threadIdx.x) * 4;
    if (e0 >= E) return;
    if (e0 + 3 < E) {
        int4 dv = *(const int4*)&ei[E + e0];
        unsigned m0 = (dmask[dv.x >> 5] >> (dv.x & 31)) & 1u;
        unsigned m1 = (dmask[dv.y >> 5] >> (dv.y & 31)) & 1u;
        unsigned m2 = (dmask[dv.z >> 5] >> (dv.z & 31)) & 1u;
        unsigned m3 = (dmask[dv.w >> 5] >> (dv.w & 31)) & 1u;
        if (m0 | m1 | m2 | m3) {
            int4 sv = *(const int4*)&ei[e0];
            if (m0) { int p = atomicAdd(nme, 1); if (p < MEDGE_CAP) medge[p] = (int)e0;     atomicOr(&smask[sv.x >> 5], 1u << (sv.x & 31)); }
            if (m1) { int p = atomicAdd(nme, 1); if (p < MEDGE_CAP) medge[p] = (int)e0 + 1; atomicOr(&smask[sv.y >> 5], 1u << (sv.y & 31)); }
            if (m2) { int p = atomicAdd(nme, 1); if (p < MEDGE_CAP) medge[p] = (int)e0 + 2; atomicOr(&smask[sv.z >> 5], 1u << (sv.z & 31)); }
            if (m3) { int p = atomicAdd(nme, 1); if (p < MEDGE_CAP) medge[p] = (int)e0 + 3; atomicOr(&smask[sv.w >> 5], 1u << (sv.w & 31)); }
        }
    } else {
        for (long e = e0; e < E; ++e) {
            int d = ei[E + e];
            if ((dmask[d >> 5] >> (d & 31)) & 1u) {
                int s = ei[e];
                int p = atomicAdd(nme, 1);
                if (p < MEDGE_CAP) medge[p] = (int)e;
                atomicOr(&smask[s >> 5], 1u << (s & 31));
            }
        }
    }
}

// ---------------------------------------------------------------------------
// bucket scatter: 4 contiguous edges/thread, int4 loads (R6-proven)
__global__ __launch_bounds__(256) void kbin(const int* __restrict__ ei, int E,
        int* __restrict__ gcur, unsigned* __restrict__ bkt) {
    __shared__ int hist[NB];
    __shared__ int base_[NB];
    int t = threadIdx.x;
    long e0 = (long)blockIdx.x * 1024 + t * 4;
    hist[t] = 0; hist[t + 256] = 0;
    __syncthreads();
    int4 dv, sv;
    int lp0 = 0, lp1 = 0, lp2 = 0, lp3 = 0;
    bool ok = e0 + 3 < E;
    if (ok) {
        dv = *(const int4*)&ei[E + e0];
        sv = *(const int4*)&ei[e0];
        lp0 = atomicAdd(&hist[dv.x >> 8], 1);
        lp1 = atomicAdd(&hist[dv.y >> 8], 1);
        lp2 = atomicAdd(&hist[dv.z >> 8], 1);
        lp3 = atomicAdd(&hist[dv.w >> 8], 1);
    }
    __syncthreads();
    { int hc = hist[t];       base_[t]       = hc ? atomicAdd(&gcur[t], hc) : 0; }
    { int hc = hist[t + 256]; base_[t + 256] = hc ? atomicAdd(&gcur[t + 256], hc) : 0; }
    __syncthreads();
    if (ok) {
        bkt[base_[dv.x >> 8] + lp0] = ((unsigned)(dv.x & 255) << 17) | (unsigned)sv.x;
        bkt[base_[dv.y >> 8] + lp1] = ((unsigned)(dv.y & 255) << 17) | (unsigned)sv.y;
        bkt[base_[dv.z >> 8] + lp2] = ((unsigned)(dv.z & 255) << 17) | (unsigned)sv.z;
        bkt[base_[dv.w >> 8] + lp3] = ((unsigned)(dv.w & 255) << 17) | (unsigned)sv.w;
    } else if (e0 < E) {
        for (long e = e0; e < E && e < e0 + 4; ++e) {
            int s = ei[e], d = ei[E + e];
            int p = atomicAdd(&gcur[d >> 8], 1);
            bkt[p] = ((unsigned)(d & 255) << 17) | (unsigned)s;
        }
    }
}

// per-bucket counting sort (256 nodes/bucket) -> rowptr + csr + nlist
__global__ __launch_bounds__(256) void kcsr(const unsigned* __restrict__ bkt,
        const int* __restrict__ bstart, const int* __restrict__ bcnt,
        const unsigned* __restrict__ dmask, const unsigned* __restrict__ smask,
        int* __restrict__ rowptr, int* __restrict__ csr,
        int* __restrict__ nlist, int* __restrict__ nlcnt, int N) {
    __shared__ int hist[256];
    __shared__ int pref[256];
    __shared__ int slist[256];
    __shared__ int lcnt, lbase;
    int b = blockIdx.x, t = threadIdx.x;
    int s0 = bstart[b], cnt = bcnt[b];
    hist[t] = 0;
    if (t == 0) lcnt = 0;
    __syncthreads();
    for (int i = t; i < cnt; i += 256)
        atomicAdd(&hist[bkt[s0 + i] >> 17], 1);
    __syncthreads();
    pref[t] = hist[t];
    __syncthreads();
    for (int o = 1; o < 256; o <<= 1) {               // inclusive scan
        int v = (t >= o) ? pref[t - o] : 0;
        __syncthreads();
        pref[t] += v;
        __syncthreads();
    }
    int excl = pref[t] - hist[t];
    int n0 = (b << 8) + t;
    if (n0 < N) {
        rowptr[n0] = s0 + excl;
        unsigned nd = ((dmask[n0 >> 5] | smask[n0 >> 5]) >> (n0 & 31)) & 1u;
        if (nd) { int p = atomicAdd(&lcnt, 1); slist[p] = n0; }
    }
    __syncthreads();
    if (t == 0) lbase = atomicAdd(nlcnt, lcnt);
    pref[t] = excl;                                   // -> bucket-relative cursor
    __syncthreads();
    if (t < lcnt) nlist[lbase + t] = slist[t];
    for (int i = t; i < cnt; i += 256) {
        unsigned v = bkt[s0 + i];
        int p = atomicAdd(&pref[v >> 17], 1);
        csr[s0 + p] = (int)(v & 0x1FFFFu);
    }
}

// ---------------------------------------------------------------------------
// mean(x[src]) -> A1 cols 64..127.  8 threads per node, 16B short8 loads.
__global__ __launch_bounds__(256) void kagg1(unsigned short* __restrict__ A1,
                                             const int* __restrict__ rowptr,
                                             const int* __restrict__ csr, int N) {
    int tid = blockIdx.x * 256 + threadIdx.x;
    int n = tid >> 3, c = tid & 7;
    if (n >= N) return;
    int beg = rowptr[n], end = rowptr[n + 1];
    float acc[8] = {0.f, 0.f, 0.f, 0.f, 0.f, 0.f, 0.f, 0.f};
    int j = beg;
    for (; j + 4 <= end; j += 4) {
        int s0 = csr[j], s1 = csr[j + 1], s2 = csr[j + 2], s3 = csr[j + 3];
        short8 v0 = *(const short8*)(A1 + (long)s0 * 128 + c * 8);
        short8 v1 = *(const short8*)(A1 + (long)s1 * 128 + c * 8);
        short8 v2 = *(const short8*)(A1 + (long)s2 * 128 + c * 8);
        short8 v3 = *(const short8*)(A1 + (long)s3 * 128 + c * 8);
#pragma unroll
        for (int k = 0; k < 8; ++k)
            acc[k] += b2f((unsigned short)v0[k]) + b2f((unsigned short)v1[k])
                    + b2f((unsigned short)v2[k]) + b2f((unsigned short)v3[k]);
    }
    for (; j < end; ++j) {
        short8 v = *(const short8*)(A1 + (long)csr[j] * 128 + c * 8);
#pragma unroll
        for (int k = 0; k < 8; ++k) acc[k] += b2f((unsigned short)v[k]);
    }
    float inv = 1.f / fmaxf((float)(end - beg), 1.f);
    unsigned short o[8];
#pragma unroll
    for (int k = 0; k < 8; ++k) o[k] = f2b(acc[k] * inv);
    *(short8*)(A1 + (long)n * 128 + 64 + c * 8) = *(const short8*)o;
}

// ---------------------------------------------------------------------------
// GEMM1: h1 = gelu(A1 @ W1 + b1), K=128, cols=128. 32 rows/wave, no LDS.
__global__ __launch_bounds__(256) void kgemm1(const unsigned short* __restrict__ A1,
                                              const unsigned short* __restrict__ B1pk,
                                              const float* __restrict__ b1,
                                              unsigned short* __restrict__ h1, int N) {
    int l = threadIdx.x & 63, wv = threadIdx.x >> 6;
    int lm = l & 15, lh = l >> 4;
    long base = (long)blockIdx.x * 128 + wv * 32;
    int r0 = (int)base + lm;      if (r0 > N - 1) r0 = N - 1;
    int r1 = (int)base + 16 + lm; if (r1 > N - 1) r1 = N - 1;
    const unsigned short* a0p = A1 + (long)r0 * 128 + lh * 8;
    const unsigned short* a1p = A1 + (long)r1 * 128 + lh * 8;
    const short8* bp = (const short8*)B1pk;
    f32x4 acc[2][8];
#pragma unroll
    for (int rg = 0; rg < 2; ++rg)
#pragma unroll
        for (int cg = 0; cg < 8; ++cg) acc[rg][cg] = (f32x4){0.f, 0.f, 0.f, 0.f};
#pragma unroll
    for (int s = 0; s < 4; ++s) {
        short8 a0 = *(const short8*)(a0p + s * 32);
        short8 a1 = *(const short8*)(a1p + s * 32);
#pragma unroll
        for (int cg = 0; cg < 8; ++cg) {
            short8 b = bp[(s * 8 + cg) * 64 + l];
            acc[0][cg] = __builtin_amdgcn_mfma_f32_16x16x32_bf16(a0, b, acc[0][cg], 0, 0, 0);
            acc[1][cg] = __builtin_amdgcn_mfma_f32_16x16x32_bf16(a1, b, acc[1][cg], 0, 0, 0);
        }
    }
#pragma unroll
    for (int cg = 0; cg < 8; ++cg) {
        float bv = b1[cg * 16 + lm];
#pragma unroll
        for (int rg = 0; rg < 2; ++rg) {
#pragma unroll
            for (int r = 0; r < 4; ++r) {
                long row = base + rg * 16 + lh * 4 + r;
                if (row < N)
                    h1[row * 128 + cg * 16 + lm] = f2b(gelu_f(acc[rg][cg][r] + bv));
            }
        }
    }
}

// GEMM2: cols 0..63 -> hsd (f32, +bc) ; cols 64..127 -> z (bf16)
__global__ __launch_bounds__(256) void kgemm2(const unsigned short* __restrict__ h1,
                                              const unsigned short* __restrict__ B2pk,
                                              const float* __restrict__ bc,
                                              float* __restrict__ hsd,
                                              unsigned short* __restrict__ z, int N) {
    int l = threadIdx.x & 63, wv = threadIdx.x >> 6;
    int lm = l & 15, lh = l >> 4;
    long base = (long)blockIdx.x * 128 + wv * 32;
    int r0 = (int)base + lm;      if (r0 > N - 1) r0 = N - 1;
    int r1 = (int)base + 16 + lm; if (r1 > N - 1) r1 = N - 1;
    const unsigned short* a0p = h1 + (long)r0 * 128 + lh * 8;
    const unsigned short* a1p = h1 + (long)r1 * 128 + lh * 8;
    const short8* bp = (const short8*)B2pk;
    f32x4 acc[2][8];
#pragma unroll
    for (int rg = 0; rg < 2; ++rg)
#pragma unroll
        for (int cg = 0; cg < 8; ++cg) acc[rg][cg] = (f32x4){0.f, 0.f, 0.f, 0.f};
#pragma unroll
    for (int s = 0; s < 4; ++s) {
        short8 a0 = *(const short8*)(a0p + s * 32);
        short8 a1 = *(const short8*)(a1p + s * 32);
#pragma unroll
        for (int cg = 0; cg < 8; ++cg) {
            short8 b = bp[(s * 8 + cg) * 64 + l];
            acc[0][cg] = __builtin_amdgcn_mfma_f32_16x16x32_bf16(a0, b, acc[0][cg], 0, 0, 0);
            acc[1][cg] = __builtin_amdgcn_mfma_f32_16x16x32_bf16(a1, b, acc[1][cg], 0, 0, 0);
        }
    }
#pragma unroll
    for (int cg = 0; cg < 4; ++cg) {          // direct part
        float bv = bc[cg * 16 + lm];
#pragma unroll
        for (int rg = 0; rg < 2; ++rg)
#pragma unroll
            for (int r = 0; r < 4; ++r) {
                long row = base + rg * 16 + lh * 4 + r;
                if (row < N) hsd[row * 64 + cg * 16 + lm] = acc[rg][cg][r] + bv;
            }
    }
#pragma unroll
    for (int cg = 4; cg < 8; ++cg) {          // neighbor part -> z (bf16)
#pragma unroll
        for (int rg = 0; rg < 2; ++rg)
#pragma unroll
            for (int r = 0; r < 4; ++r) {
                long row = base + rg * 16 + lh * 4 + r;
                if (row < N) z[row * 64 + (cg - 4) * 16 + lm] = f2b(acc[rg][cg][r]);
            }
    }
}

// ---------------------------------------------------------------------------
// finalv = hsd + mean(z[src]) for LISTED nodes only.  8 threads/node.
__global__ __launch_bounds__(256) void kagg3(const unsigned short* __restrict__ z,
                                             const float* __restrict__ hsd,
                                             const int* __restrict__ rowptr,
                                             const int* __restrict__ csr,
                                             const int* __restrict__ nlist,
                                             const int* __restrict__ nlcnt,
                                             float* __restrict__ finalv) {
    int cnt = *nlcnt;
    int slots = (gridDim.x * 256) >> 3;
    int slot = (blockIdx.x * 256 + threadIdx.x) >> 3;
    int c = threadIdx.x & 7;
    for (int li = slot; li < cnt; li += slots) {
        int n = nlist[li];
        int beg = rowptr[n], end = rowptr[n + 1];
        float acc[8] = {0.f, 0.f, 0.f, 0.f, 0.f, 0.f, 0.f, 0.f};
        int j = beg;
        for (; j + 4 <= end; j += 4) {
            int s0 = csr[j], s1 = csr[j + 1], s2 = csr[j + 2], s3 = csr[j + 3];
            short8 v0 = *(const short8*)(z + (long)s0 * 64 + c * 8);
            short8 v1 = *(const short8*)(z + (long)s1 * 64 + c * 8);
            short8 v2 = *(const short8*)(z + (long)s2 * 64 + c * 8);
            short8 v3 = *(const short8*)(z + (long)s3 * 64 + c * 8);
#pragma unroll
            for (int k = 0; k < 8; ++k)
                acc[k] += b2f((unsigned short)v0[k]) + b2f((unsigned short)v1[k])
                        + b2f((unsigned short)v2[k]) + b2f((unsigned short)v3[k]);
        }
        for (; j < end; ++j) {
            short8 v = *(const short8*)(z + (long)csr[j] * 64 + c * 8);
#pragma unroll
            for (int k = 0; k < 8; ++k) acc[k] += b2f((unsigned short)v[k]);
        }
        float inv = 1.f / fmaxf((float)(end - beg), 1.f);
        float4 o0, o1;
        const float4* hp = (const float4*)(hsd + (long)n * 64 + c * 8);
        float4 h0 = hp[0], h1v = hp[1];
        o0.x = h0.x + acc[0] * inv; o0.y = h0.y + acc[1] * inv;
        o0.z = h0.z + acc[2] * inv; o0.w = h0.w + acc[3] * inv;
        o1.x = h1v.x + acc[4] * inv; o1.y = h1v.y + acc[5] * inv;
        o1.z = h1v.z + acc[6] * inv; o1.w = h1v.w + acc[7] * inv;
        float4* op = (float4*)(finalv + (long)n * 64 + c * 8);
        op[0] = o0; op[1] = o1;
    }
}

// ---------------------------------------------------------------------------
__global__ void kedgemax(const int* __restrict__ nme, const int* __restrict__ medge,
                         const int* __restrict__ ei, const float* __restrict__ et,
                         const float* __restrict__ finalv,
                         const float* __restrict__ wt, const float* __restrict__ bt,
                         unsigned* __restrict__ outm, int E) {
    int nm = *nme; if (nm > MEDGE_CAP) nm = MEDGE_CAP;
    for (int i = blockIdx.x * blockDim.x + threadIdx.x; i < nm;
         i += gridDim.x * blockDim.x) {
        int e = medge[i];
        int s = ei[e], d = ei[E + e];
        float tm = et[e];
        const float4* a4 = (const float4*)(finalv + (long)s * 64);       // hs
        const float4* b4 = (const float4*)(finalv + (long)d * 64 + 32);  // hd
        const float4* wt4 = (const float4*)wt;
        const float4* bt4 = (const float4*)bt;
        unsigned* om = outm + (long)d * 32;
#pragma unroll
        for (int c4 = 0; c4 < 8; ++c4) {
            float4 a = a4[c4], b = b4[c4], w = wt4[c4], bb = bt4[c4];
            float v0 = gelu_f(a.x + b.x + tm * w.x + bb.x);
            float v1 = gelu_f(a.y + b.y + tm * w.y + bb.y);
            float v2 = gelu_f(a.z + b.z + tm * w.z + bb.z);
            float v3 = gelu_f(a.w + b.w + tm * w.w + bb.w);
            atomicMax(om + c4 * 4 + 0, enc_f32(v0));
            atomicMax(om + c4 * 4 + 1, enc_f32(v1));
            atomicMax(om + c4 * 4 + 2, enc_f32(v2));
            atomicMax(om + c4 * 4 + 3, enc_f32(v3));
        }
    }
}

__global__ void kout(const int* __restrict__ mask, const unsigned* __restrict__ outm,
                     float* __restrict__ out, int M) {
    int idx = blockIdx.x * blockDim.x + threadIdx.x;
    if (idx >= M * 32) return;
    int i = idx >> 5, c = idx & 31;
    float f = dec_f32(outm[(long)mask[i] * 32 + c]);
    out[idx] = isfinite(f) ? f : 0.0f;
}

// ---------------------------------------------------------------------------
extern "C" void kernel_launch(void* const* d_in, const int* in_sizes, int n_in,
                              void* d_out, int out_size, void* d_ws, size_t ws_size,
                              hipStream_t stream) {
    const float* x   = (const float*)d_in[0];
    const int*   ei  = (const int*)d_in[1];
    const float* et  = (const float*)d_in[2];
    const int*   mask= (const int*)d_in[3];
    const float* W1r = (const float*)d_in[4];
    const float* W1n = (const float*)d_in[5];
    const float* b1  = (const float*)d_in[6];
    const float* W2r = (const float*)d_in[7];
    const float* W2n = (const float*)d_in[8];
    const float* b2  = (const float*)d_in[9];
    const float* Wts = (const float*)d_in[10];
    const float* Wtd = (const float*)d_in[11];
    const float* wt  = (const float*)d_in[12];
    const float* bt  = (const float*)d_in[13];

    int N = in_sizes[0] / 64;
    int E = in_sizes[1] / 2;
    int M = in_sizes[3];

    float* ws = (float*)d_ws;
    size_t off = 0;
    auto pad4 = [](size_t w) { return (w + 3) & ~(size_t)3; };
    size_t mw = (((size_t)N + 31) / 32 + 15) & ~(size_t)15;   // mask words, pad16
    // --- zeroed region (contiguous from ws[0]) ---
    unsigned* dmask = (unsigned*)(ws + off); off += mw;
    unsigned* smask = (unsigned*)(ws + off); off += mw;
    int*      bcnt  = (int*)(ws + off);      off += NB;
    int*      nme   = (int*)(ws + off);      off += 4;
    int*      nlcnt = (int*)(ws + off);      off += 4;
    size_t zero_words = off;                 // multiple of 8 -> /4 float4s
    // --- rest (not zeroed) ---
    int*      bstart= (int*)(ws + off);      off += NB;
    int*      gcur  = (int*)(ws + off);      off += NB;
    int*      rowptr= (int*)(ws + off);      off += pad4(N + 1);
    int*      csr   = (int*)(ws + off);      off += pad4(E);
    unsigned* bkt   = (unsigned*)(ws + off); off += pad4(E);
    int*      medge = (int*)(ws + off);      off += MEDGE_CAP;
    int*      nlist = (int*)(ws + off);      off += pad4(N);
    float*    bc    = ws + off;              off += 64;
    unsigned short* B1pk = (unsigned short*)(ws + off); off += 8192;
    unsigned short* B2pk = (unsigned short*)(ws + off); off += 8192;
    unsigned short* A1   = (unsigned short*)(ws + off); off += (size_t)N * 64;
    unsigned short* h1   = (unsigned short*)(ws + off); off += (size_t)N * 64;
    float*    hsd   = ws + off;              off += (size_t)N * 64;
    unsigned short* zb   = (unsigned short*)(ws + off); off += (size_t)N * 32;  // FIXED: N*64 bf16 = N*32 words
    float*    finalv= ws + off;              off += (size_t)N * 64;
    unsigned* outm  = (unsigned*)(ws + off); off += (size_t)N * 32;

    long n4z = (long)(zero_words / 4);
    long init_total = n4z + (long)N * 16;
    int fb = (M + 255) / 256;                         // flag blocks in kmix1
    int hb = (int)((E + HEB - 1) / HEB);              // hist blocks in kmix1
    int medb = (int)(((long)E + 1023) / 1024);        // medge blocks in kmix2
    int binb = (int)(((long)E + 1023) / 1024);        // kbin blocks
    int nb_used = (N + 255) >> 8;

    kinit<<<(int)((init_total + 255) / 256), 256, 0, stream>>>(
        (float4*)ws, n4z, x, A1, N);
    kmix1<<<129 + fb + hb, 256, 0, stream>>>(W1r, W1n, W2r, W2n, b2, Wts, Wtd,
        ei, E, mask, M, fb, B1pk, B2pk, bc, dmask, outm, bcnt);
    kmix2<<<medb + 1, 256, 0, stream>>>(ei, E, dmask, smask, nme, medge,
        bcnt, bstart, gcur, rowptr, N, medb);
    kbin<<<binb, 256, 0, stream>>>(ei, E, gcur, bkt);
    kcsr<<<nb_used, 256, 0, stream>>>(bkt, bstart, bcnt, dmask, smask,
                                      rowptr, csr, nlist, nlcnt, N);

    kagg1<<<(N * 8 + 255) / 256, 256, 0, stream>>>(A1, rowptr, csr, N);
    kgemm1<<<(N + 127) / 128, 256, 0, stream>>>(A1, B1pk, b1, h1, N);
    kgemm2<<<(N + 127) / 128, 256, 0, stream>>>(h1, B2pk, bc, hsd, zb, N);
    kagg3<<<512, 256, 0, stream>>>(zb, hsd, rowptr, csr, nlist, nlcnt, finalv);

    kedgemax<<<128, 256, 0, stream>>>(nme, medge, ei, et, finalv, wt, bt, outm, E);
    kout<<<(M * 32 + 255) / 256, 256, 0, stream>>>(mask, outm, (float*)d_out, M);
}